// Round 9
// baseline (346.699 us; speedup 1.0000x reference)
//
#include <hip/hip_runtime.h>

// MultiHeadSelfAttention: B=4, C=256, S=4096, heads=8, d=32.
// 5-kernel pipeline. k_attn uses 32x32x16 MFMAs with a register-direct
// QK->softmax->PV path: QK C-layout (A=K m=key, B=Q n=q) feeds PV's B operand
// (B=P) with NO data movement -- C reg j+8p == PV-half-p B reg j under key
// permutation phi, absorbed by storing V column-permuted ([0,2,1,3] 4-chunk
// order per 16-key group). No LDS in the attention main loop.
// __launch_bounds__(256,4) pins unified VGPR+AGPR <= 128 -> >=4 waves/SIMD.

typedef __attribute__((ext_vector_type(8))) short short8;   // 8 x bf16 frag
typedef __attribute__((ext_vector_type(4))) float f4;
typedef __attribute__((ext_vector_type(16))) float f16v;    // 32x32 C/D

__device__ __forceinline__ short f2bs(float f) {  // fp32 -> bf16 (RNE)
  union { float f; unsigned u; } v; v.f = f;
  unsigned r = v.u + 0x7FFFu + ((v.u >> 16) & 1u);
  return (short)(r >> 16);
}

__device__ __forceinline__ int pkrne(float a, float b) {
  return (int)((unsigned short)f2bs(a) | ((unsigned)f2bs(b) << 16));
}

// pack hi16(lo+0x8000), hi16(hi+0x8000) -> dword (round-half-up): 3 VALU
__device__ __forceinline__ int pkhu(float lo, float hi) {
  union { float f; unsigned u; } a, b; a.f = lo; b.f = hi;
  return (int)__builtin_amdgcn_perm(b.u + 0x8000u, a.u + 0x8000u, 0x07060302u);
}

__device__ __forceinline__ short8 mk8(int a, int b, int c, int d) {
  int4 t; t.x = a; t.y = b; t.z = c; t.w = d;
  short8 r; __builtin_memcpy(&r, &t, 16); return r;
}

// ---------------------------------------------------------------- prep: weights
__global__ __launch_bounds__(256) void k_prep_w(
    const float* __restrict__ wq, const float* __restrict__ wp,
    short* __restrict__ wqb, short* __restrict__ wpb) {
  const int i = blockIdx.x * 256 + threadIdx.x;
  const int NQ = 768 * 256 / 4;
  f4 v; short* dst; int off;
  if (i < NQ) { v = ((const f4*)wq)[i]; dst = wqb; off = i * 4; }
  else        { v = ((const f4*)wp)[i - NQ]; dst = wpb; off = (i - NQ) * 4; }
  int2 pr; pr.x = pkrne(v[0], v[1]); pr.y = pkrne(v[2], v[3]);
  *(int2*)(dst + off) = pr;
}

// ---------------------------------------------------------------- prep: x -> xT
__global__ __launch_bounds__(256) void k_prep_x(
    const float* __restrict__ x, short* __restrict__ xT) {
  const int t = threadIdx.x;
  const int b = blockIdx.z, c0 = blockIdx.y * 64, s0 = blockIdx.x * 64;
  __shared__ __align__(16) short tile[64 * 64];
#pragma unroll
  for (int pass = 0; pass < 4; ++pass) {
    const int cl = pass * 16 + (t >> 4);
    const int sl = (t & 15) * 4;
    f4 v = *(const f4*)(x + ((size_t)(b * 256 + c0 + cl)) * 4096 + s0 + sl);
#pragma unroll
    for (int k = 0; k < 4; ++k) {
      const int s = sl + k;
      tile[s * 64 + (cl ^ ((s & 7) << 3))] = f2bs(v[k]);
    }
  }
  __syncthreads();
#pragma unroll
  for (int i = 0; i < 2; ++i) {
    const int s = t >> 2;
    const int gc = (t & 3) + i * 4;
    const int gg = gc ^ (s & 7);
    short8 row = *(const short8*)(tile + s * 64 + gg * 8);
    *(short8*)(xT + ((size_t)(b * 4096 + s0 + s)) * 256 + c0 + gc * 8) = row;
  }
}

// ---------------------------------------------------------------- kernel: qkv
// Wave = 32 j x 64 s (2 A-frags, 8 MFMA per 32-c step, 6 b128 loads).
// Block = 4 waves = 128 j x 64 s. Grid (256 s-tiles, 6 j-tiles).
// 32-j waves are head-aligned: V epilogue covers the full d=0..31.
__global__ __launch_bounds__(256) void k_qkv(
    const short* __restrict__ xT, const short* __restrict__ wqb,
    const float* __restrict__ bias,
    short* __restrict__ Qr, short* __restrict__ Kq, short* __restrict__ Vp) {
  const int tid = threadIdx.x;
  const int L = tid & 63, wv = tid >> 6;
  const int ln15 = L & 15, quad = L >> 4;
  const int mt = blockIdx.x;
  const int b = mt >> 6;
  const int s0 = (mt & 63) << 6;
  const int jw = blockIdx.y * 128 + wv * 32;

  __shared__ __align__(16) short tl[4][2048];  // per-wave V transpose (32d x 64s)

  f4 acc[2][4] = {{{0,0,0,0},{0,0,0,0},{0,0,0,0},{0,0,0,0}},
                  {{0,0,0,0},{0,0,0,0},{0,0,0,0},{0,0,0,0}}};
  const short* wb0 = wqb + (jw + ln15) * 256 + quad * 8;
  const short* wb1 = wb0 + 16 * 256;
  const short* xb = xT + (size_t)(b * 4096 + s0 + ln15) * 256 + quad * 8;

#pragma unroll 2
  for (int cb = 0; cb < 256; cb += 32) {
    short8 af0 = *(const short8*)(wb0 + cb);
    short8 af1 = *(const short8*)(wb1 + cb);
#pragma unroll
    for (int sub = 0; sub < 4; ++sub) {
      short8 bfr = *(const short8*)(xb + sub * (16 * 256) + cb);
      acc[0][sub] = __builtin_amdgcn_mfma_f32_16x16x32_bf16(af0, bfr, acc[0][sub], 0, 0, 0);
      acc[1][sub] = __builtin_amdgcn_mfma_f32_16x16x32_bf16(af1, bfr, acc[1][sub], 0, 0, 0);
    }
  }
  float bj[2][4];
#pragma unroll
  for (int j2 = 0; j2 < 2; ++j2)
#pragma unroll
    for (int r = 0; r < 4; ++r) bj[j2][r] = bias[jw + j2 * 16 + quad * 4 + r];

  const int type = jw >> 8;  // 0=Q 1=K 2=V
  const int bh = b * 8 + ((jw & 255) >> 5);

  if (type != 2) {
    const float qsc = 0.17677669529663689f * 1.44269504088896f;
    const float mul = (type == 0) ? qsc : 1.0f;
    short* dst = (type == 0) ? Qr : Kq;
#pragma unroll
    for (int j2 = 0; j2 < 2; ++j2)
#pragma unroll
      for (int sub = 0; sub < 4; ++sub) {
        float v0 = (acc[j2][sub][0] + bj[j2][0]) * mul;
        float v1 = (acc[j2][sub][1] + bj[j2][1]) * mul;
        float v2 = (acc[j2][sub][2] + bj[j2][2]) * mul;
        float v3 = (acc[j2][sub][3] + bj[j2][3]) * mul;
        int2 pr; pr.x = pkhu(v0, v1); pr.y = pkhu(v2, v3);
        *(int2*)(dst + (size_t)(bh * 4096 + s0 + sub * 16 + ln15) * 32 +
                 j2 * 16 + quad * 4) = pr;
      }
  } else {
    // V: transpose to (d, s) through per-wave LDS, then store with the
    // PV-A-frag column permutation ([0,2,1,3] 4-chunk order, self-inverse).
    short* tv = tl[wv];
#pragma unroll
    for (int j2 = 0; j2 < 2; ++j2)
#pragma unroll
      for (int sub = 0; sub < 4; ++sub) {
        const int s = sub * 16 + ln15;
#pragma unroll
        for (int r = 0; r < 4; ++r) {
          const int dl = j2 * 16 + quad * 4 + r;
          tv[dl * 64 + ((((s >> 3) ^ dl) & 7) << 3) + (s & 7)] =
              f2bs(acc[j2][sub][r] + bj[j2][r]);
        }
      }
#pragma unroll
    for (int i = 0; i < 4; ++i) {
      const int dl = i * 8 + (L >> 3);
      const int gs = L & 7;
      const int gg = gs ^ (dl & 7);
      short8 row = *(const short8*)(tv + dl * 64 + gg * 8);
      union { short8 s; int4 i4; } u; u.s = row;
      short* vrow = Vp + (size_t)(bh * 32 + dl) * 4096 + s0 + (gs >> 1) * 16;
      const int o0 = (gs & 1) ? 4 : 0;
      const int o1 = (gs & 1) ? 12 : 8;
      int2 lo; lo.x = u.i4.x; lo.y = u.i4.y;
      int2 hi; hi.x = u.i4.z; hi.y = u.i4.w;
      *(int2*)(vrow + o0) = lo;
      *(int2*)(vrow + o1) = hi;
    }
  }
}

// ---------------------------------------------------------------- kernel: attn
// Block = 4 waves: wave wv -> q-tile (wv&1), key-half (wv>>1); 32 q per wave.
// Per 32-key block: QK = 2x mfma_32x32x16 -> 4 groups of (4 exp2 -> 2 pkhu)
// -> PV = 2x mfma_32x32x16. Register-only softmax path.
__global__ __launch_bounds__(256, 4) void k_attn(
    const short* __restrict__ Qr, const short* __restrict__ Kq,
    const short* __restrict__ Vp, short* __restrict__ O) {
  const int tid = threadIdx.x;
  const int L = tid & 63, wv = tid >> 6;
  const int l31 = L & 31, lh = L >> 5;
  const int bh = blockIdx.y;
  const int b = bh >> 3, hd = bh & 7;
  const int qt = wv & 1, half = wv >> 1;
  const int qb = blockIdx.x * 64 + qt * 32;

  const short* Qb = Qr + (size_t)bh * 4096 * 32;
  const short* Kb = Kq + (size_t)bh * 4096 * 32 + half * (2048 * 32);
  const short* Vb = Vp + (size_t)bh * 32 * 4096 + half * 2048;

  __shared__ float cmb[2][32 * 32];
  __shared__ float l_up[2][32];

  short8 qf0 = *(const short8*)(Qb + (qb + l31) * 32 + 8 * lh);
  short8 qf1 = *(const short8*)(Qb + (qb + l31) * 32 + 16 + 8 * lh);

  f16v acc = {0,0,0,0,0,0,0,0,0,0,0,0,0,0,0,0};
  const f16v z16 = {0,0,0,0,0,0,0,0,0,0,0,0,0,0,0,0};
  float lsum = 0.f;

  const short* kp = Kb + l31 * 32 + 8 * lh;            // row=key, col=d
  const short* vpp = Vb + (size_t)l31 * 4096 + 8 * lh; // row=d, col=pos

#pragma unroll 2
  for (int kb = 0; kb < 2048; kb += 32) {
    short8 kf0 = *(const short8*)(kp + kb * 32);
    short8 kf1 = *(const short8*)(kp + kb * 32 + 16);
    short8 vf0 = *(const short8*)(vpp + kb);
    short8 vf1 = *(const short8*)(vpp + kb + 16);
    f16v sc = __builtin_amdgcn_mfma_f32_32x32x16_bf16(kf0, qf0, z16, 0, 0, 0);
    sc = __builtin_amdgcn_mfma_f32_32x32x16_bf16(kf1, qf1, sc, 0, 0, 0);
    int pd[8];
    float ls = 0.f;
#pragma unroll
    for (int g = 0; g < 4; ++g) {  // retire sc 4 scores at a time
      float a = __builtin_amdgcn_exp2f(sc[4 * g + 0]);
      float c = __builtin_amdgcn_exp2f(sc[4 * g + 1]);
      float d = __builtin_amdgcn_exp2f(sc[4 * g + 2]);
      float e = __builtin_amdgcn_exp2f(sc[4 * g + 3]);
      ls += (a + c) + (d + e);
      pd[2 * g] = pkhu(a, c);
      pd[2 * g + 1] = pkhu(d, e);
    }
    lsum += ls;
    short8 pb0 = mk8(pd[0], pd[1], pd[2], pd[3]);
    short8 pb1 = mk8(pd[4], pd[5], pd[6], pd[7]);
    acc = __builtin_amdgcn_mfma_f32_32x32x16_bf16(vf0, pb0, acc, 0, 0, 0);
    acc = __builtin_amdgcn_mfma_f32_32x32x16_bf16(vf1, pb1, acc, 0, 0, 0);
  }

  const float lf = lsum + __shfl_xor(lsum, 32);

  if (half == 1) {
    float* cw = cmb[qt];
#pragma unroll
    for (int r = 0; r < 16; ++r) {
      const int d = (r & 3) + 8 * (r >> 2) + 4 * lh;
      cw[l31 * 32 + (d ^ l31)] = acc[r];
    }
    if (lh == 0) l_up[qt][l31] = lf;
  }
  __syncthreads();
  if (half == 0) {
    const float* cu = cmb[qt];
    const float rl = 1.0f / (lf + l_up[qt][l31]);
    short* op = O + (size_t)(b * 4096 + qb + l31) * 256 + hd * 32;
#pragma unroll
    for (int g = 0; g < 4; ++g) {
      const int d0 = 4 * lh + 8 * g;
      const float o0 = (acc[4 * g + 0] + cu[l31 * 32 + ((d0 + 0) ^ l31)]) * rl;
      const float o1 = (acc[4 * g + 1] + cu[l31 * 32 + ((d0 + 1) ^ l31)]) * rl;
      const float o2 = (acc[4 * g + 2] + cu[l31 * 32 + ((d0 + 2) ^ l31)]) * rl;
      const float o3 = (acc[4 * g + 3] + cu[l31 * 32 + ((d0 + 3) ^ l31)]) * rl;
      int2 st; st.x = pkrne(o0, o1); st.y = pkrne(o2, o3);
      *(int2*)(op + d0) = st;
    }
  }
}

// ---------------------------------------------------------------- kernel: proj
// Wave = 32 s x 64 c (2 A-frags, 8 MFMA per 32-c step). Block = 128 s x 64 c.
__global__ __launch_bounds__(256) void k_proj(
    const short* __restrict__ O, const short* __restrict__ wpb,
    const float* __restrict__ bias, float* __restrict__ out) {
  const int tid = threadIdx.x;
  const int L = tid & 63, wv = tid >> 6;
  const int ln15 = L & 15, quad = L >> 4;
  const int m0 = blockIdx.x * 128 + wv * 32;
  const int n0 = blockIdx.y << 6;
  const int b = m0 >> 12, s0 = m0 & 4095;

  f4 acc[2][4] = {{{0,0,0,0},{0,0,0,0},{0,0,0,0},{0,0,0,0}},
                  {{0,0,0,0},{0,0,0,0},{0,0,0,0},{0,0,0,0}}};
  const short* Ob0 = O + (size_t)(m0 + ln15) * 256 + quad * 8;
  const short* Ob1 = Ob0 + 16 * 256;
  const short* wb = wpb + (n0 + ln15) * 256 + quad * 8;

#pragma unroll 2
  for (int cb = 0; cb < 256; cb += 32) {
    short8 af0 = *(const short8*)(Ob0 + cb);
    short8 af1 = *(const short8*)(Ob1 + cb);
#pragma unroll
    for (int sub = 0; sub < 4; ++sub) {
      short8 bfr = *(const short8*)(wb + sub * (16 * 256) + cb);
      acc[0][sub] = __builtin_amdgcn_mfma_f32_16x16x32_bf16(af0, bfr, acc[0][sub], 0, 0, 0);
      acc[1][sub] = __builtin_amdgcn_mfma_f32_16x16x32_bf16(af1, bfr, acc[1][sub], 0, 0, 0);
    }
  }
#pragma unroll
  for (int j2 = 0; j2 < 2; ++j2)
#pragma unroll
    for (int sub = 0; sub < 4; ++sub) {
      const int c = n0 + sub * 16 + ln15;
      const float bv = bias[c];
      f4 v;
#pragma unroll
      for (int r = 0; r < 4; ++r) v[r] = acc[j2][sub][r] + bv;
      *(f4*)(out + (size_t)b * (256 * 4096) + (size_t)c * 4096 +
             s0 + j2 * 16 + quad * 4) = v;
    }
}

// ---------------------------------------------------------------- launcher
extern "C" void kernel_launch(void* const* d_in, const int* in_sizes, int n_in,
                              void* d_out, int out_size, void* d_ws, size_t ws_size,
                              hipStream_t stream) {
  const float* x      = (const float*)d_in[0];
  const float* w_qkv  = (const float*)d_in[1];
  const float* b_qkv  = (const float*)d_in[2];
  const float* w_proj = (const float*)d_in[3];
  const float* b_proj = (const float*)d_in[4];
  float* out = (float*)d_out;

  const size_t SEG = (size_t)4 * 8 * 4096 * 32;  // 4.19M bf16 elems = 8 MiB
  short* Qr  = (short*)d_ws;
  short* Kq  = Qr + SEG;
  short* Vp  = Kq + SEG;
  short* OX  = Vp + SEG;          // xT (b,s,c) until qkv done, then O (b,s,c)
  short* wqb = OX + SEG;
  short* wpb = wqb + 768 * 256;

  k_prep_w<<<256, 256, 0, stream>>>(w_qkv, w_proj, wqb, wpb);
  k_prep_x<<<dim3(64, 4, 4), 256, 0, stream>>>(x, OX);
  k_qkv <<<dim3(256, 6),  256, 0, stream>>>(OX, wqb, b_qkv, Qr, Kq, Vp);
  k_attn<<<dim3(64, 32),  256, 0, stream>>>(Qr, Kq, Vp, OX);
  k_proj<<<dim3(128, 4),  256, 0, stream>>>(OX, wpb, b_proj, out);
}